// Round 9
// baseline (279.799 us; speedup 1.0000x reference)
//
#include <hip/hip_runtime.h>

#define CC 96
#define C3 288
#define HH 256
#define WW 256
#define HWC 65536
#define NHEADS 8
#define W2 32

typedef __bf16 bf16x8 __attribute__((ext_vector_type(8)));
typedef float f32x4 __attribute__((ext_vector_type(4)));
typedef unsigned short us8v __attribute__((ext_vector_type(8)));

__device__ __forceinline__ float bf2f(unsigned short u) {
  return __uint_as_float(((unsigned)u) << 16);
}
__device__ __forceinline__ unsigned short f2bf(float f) {
  unsigned u = __float_as_uint(f);
  unsigned r = u + 0x7fffu + ((u >> 16) & 1u);
  return (unsigned short)(r >> 16);
}

// K1 v4b: qkv conv1x1 via bf16 MFMA. 64-px tiles x 8, pipelined, 27KB LDS.
// grid (128, 3, bc), block 256 (4 waves: 2M x 2N). W-frags in regs.
// tD spans BOTH As buffers (pitch 72, 16B-aligned rows); barrier after readback.
__global__ __launch_bounds__(256, 4) void k1_qkv_mfma(
    const float* __restrict__ x, const float* __restrict__ qw,
    const float* __restrict__ qb, unsigned short* __restrict__ pre, int b0)
{
  __shared__ __align__(16) unsigned short As2[2][64 * 106];
  const int t = threadIdx.x;
  const int o0 = blockIdx.y * 96;
  const int bz = blockIdx.z;
  const float* xb = x + (size_t)(b0 + bz) * CC * HWC;

  const int wave = t >> 6, lane = t & 63;
  const int wm = wave & 1, wn = wave >> 1;
  const int row = lane & 15, kg = lane >> 4;

  bf16x8 bfr[3][3];
  float bias[3];
#pragma unroll
  for (int nt = 0; nt < 3; ++nt) {
    int ocl = wn * 48 + nt * 16 + row;
    bias[nt] = qb[o0 + ocl];
#pragma unroll
    for (int kk = 0; kk < 3; ++kk) {
      const float* wp = qw + (size_t)(o0 + ocl) * 96 + kk * 32 + kg * 8;
      float4 w0 = *reinterpret_cast<const float4*>(wp);
      float4 w1 = *reinterpret_cast<const float4*>(wp + 4);
      us8v u;
      u[0] = f2bf(w0.x); u[1] = f2bf(w0.y); u[2] = f2bf(w0.z); u[3] = f2bf(w0.w);
      u[4] = f2bf(w1.x); u[5] = f2bf(w1.y); u[6] = f2bf(w1.z); u[7] = f2bf(w1.w);
      bfr[kk][nt] = *reinterpret_cast<bf16x8*>(&u);
    }
  }

  int sic[3], sp4[3];
#pragma unroll
  for (int r = 0; r < 3; ++r) {
    int lin = r * 256 + t;
    sic[r] = lin >> 4;          // ic-pair 0..47
    sp4[r] = (lin & 15) * 4;    // px 0..60
  }

  int p0 = blockIdx.x * 512;
  float4 va0[3], va1[3];
#pragma unroll
  for (int r = 0; r < 3; ++r) {
    va0[r] = *reinterpret_cast<const float4*>(xb + (size_t)(2 * sic[r]) * HWC + p0 + sp4[r]);
    va1[r] = *reinterpret_cast<const float4*>(xb + (size_t)(2 * sic[r] + 1) * HWC + p0 + sp4[r]);
  }

  for (int i = 0; i < 8; ++i) {
    unsigned short* Ac = As2[i & 1];
#pragma unroll
    for (int r = 0; r < 3; ++r) {
      float a0[4] = {va0[r].x, va0[r].y, va0[r].z, va0[r].w};
      float a1[4] = {va1[r].x, va1[r].y, va1[r].z, va1[r].w};
#pragma unroll
      for (int j = 0; j < 4; ++j) {
        unsigned pk = (unsigned)f2bf(a0[j]) | ((unsigned)f2bf(a1[j]) << 16);
        *reinterpret_cast<unsigned*>(&Ac[(sp4[r] + j) * 106 + 2 * sic[r]]) = pk;
      }
    }
    if (i < 7) {
      int p0n = p0 + 64;
#pragma unroll
      for (int r = 0; r < 3; ++r) {
        va0[r] = *reinterpret_cast<const float4*>(xb + (size_t)(2 * sic[r]) * HWC + p0n + sp4[r]);
        va1[r] = *reinterpret_cast<const float4*>(xb + (size_t)(2 * sic[r] + 1) * HWC + p0n + sp4[r]);
      }
    }
    __syncthreads();

    f32x4 acc[2][3];
#pragma unroll
    for (int mt = 0; mt < 2; ++mt)
#pragma unroll
      for (int nt = 0; nt < 3; ++nt) acc[mt][nt] = (f32x4){0.f, 0.f, 0.f, 0.f};
#pragma unroll
    for (int kk = 0; kk < 3; ++kk) {
      bf16x8 a[2];
#pragma unroll
      for (int mt = 0; mt < 2; ++mt)
        a[mt] = *reinterpret_cast<const bf16x8*>(
            &Ac[(wm * 32 + mt * 16 + row) * 106 + kk * 32 + kg * 8]);
#pragma unroll
      for (int mt = 0; mt < 2; ++mt)
#pragma unroll
        for (int nt = 0; nt < 3; ++nt)
          acc[mt][nt] = __builtin_amdgcn_mfma_f32_16x16x32_bf16(
              a[mt], bfr[kk][nt], acc[mt][nt], 0, 0, 0);
    }
    __syncthreads();   // MFMA reads of Ac done; tD spans both buffers

    unsigned short* tD = (unsigned short*)As2;   // [96][72], 6912 <= 13568 shorts
#pragma unroll
    for (int nt = 0; nt < 3; ++nt) {
      int ocl = wn * 48 + nt * 16 + row;
      float bv = bias[nt];
#pragma unroll
      for (int mt = 0; mt < 2; ++mt) {
        int pxl = wm * 32 + mt * 16 + kg * 4;
        f32x4 v = acc[mt][nt];
        unsigned pk0 = (unsigned)f2bf(v[0] + bv) | ((unsigned)f2bf(v[1] + bv) << 16);
        unsigned pk1 = (unsigned)f2bf(v[2] + bv) | ((unsigned)f2bf(v[3] + bv) << 16);
        *reinterpret_cast<unsigned*>(&tD[ocl * 72 + pxl]) = pk0;
        *reinterpret_cast<unsigned*>(&tD[ocl * 72 + pxl + 2]) = pk1;
      }
    }
    __syncthreads();
    unsigned short* preb = pre + ((size_t)bz * C3 + o0) * HWC + p0;
#pragma unroll
    for (int r = 0; r < 3; ++r) {
      int lin = r * 256 + t;
      int oc = lin >> 3, ch = lin & 7;
      us8v v = *reinterpret_cast<const us8v*>(&tD[oc * 72 + ch * 8]);
      *reinterpret_cast<us8v*>(preb + (size_t)oc * HWC + ch * 8) = v;
    }
    __syncthreads();   // readback done before next cvt overwrites the span
    p0 += 64;
  }
}

// K2: depthwise 3x3 + bias, LDS-free register-rolling. grid (288, 8, bc).
__global__ __launch_bounds__(256) void k2_dw(
    const unsigned short* __restrict__ pre, const float* __restrict__ dww,
    const float* __restrict__ dwb, unsigned short* __restrict__ dwo)
{
  const int t = threadIdx.x;
  const int c3 = blockIdx.x;
  const int hb = blockIdx.y;
  const int bz = blockIdx.z;
  const size_t choff = ((size_t)bz * C3 + c3) * HWC;
  const int team = t >> 5, tl = t & 31;
  const int h0 = hb * 32 + team * 4;

  us8v rin[6];
#pragma unroll
  for (int r = 0; r < 6; ++r) {
    int hh = h0 - 1 + r;
    if (hh >= 0 && hh < HH)
      rin[r] = *reinterpret_cast<const us8v*>(pre + choff + (size_t)hh * WW + tl * 8);
    else
      rin[r] = (us8v){0, 0, 0, 0, 0, 0, 0, 0};
  }

  float wg[9];
#pragma unroll
  for (int i = 0; i < 9; ++i) wg[i] = dww[c3 * 9 + i];
  const float bias = dwb[c3];

  float f[6][8];
  float lf[6], rt[6];
#pragma unroll
  for (int r = 0; r < 6; ++r) {
#pragma unroll
    for (int j = 0; j < 8; ++j) f[r][j] = bf2f(rin[r][j]);
    float l = __shfl_up(f[r][7], 1, 32);
    float rr = __shfl_down(f[r][0], 1, 32);
    lf[r] = (tl == 0) ? 0.f : l;
    rt[r] = (tl == 31) ? 0.f : rr;
  }

#pragma unroll
  for (int orow = 0; orow < 4; ++orow) {
    float o[8];
#pragma unroll
    for (int j = 0; j < 8; ++j) o[j] = bias;
#pragma unroll
    for (int k = 0; k < 3; ++k) {
      const int r = orow + k;
      const float w0 = wg[k * 3 + 0], w1 = wg[k * 3 + 1], w2 = wg[k * 3 + 2];
      o[0] = fmaf(lf[r], w0, fmaf(f[r][0], w1, fmaf(f[r][1], w2, o[0])));
#pragma unroll
      for (int j = 1; j < 7; ++j)
        o[j] = fmaf(f[r][j - 1], w0, fmaf(f[r][j], w1, fmaf(f[r][j + 1], w2, o[j])));
      o[7] = fmaf(f[r][6], w0, fmaf(f[r][7], w1, fmaf(rt[r], w2, o[7])));
    }
    us8v u;
#pragma unroll
    for (int j = 0; j < 8; ++j) u[j] = f2bf(o[j]);
    *reinterpret_cast<us8v*>((unsigned short*)dwo + choff + (size_t)(h0 + orow) * WW + tl * 8) = u;
  }
}

// K3 v2: partial Gram per (c,head,b), h chunked 2x128 (32KB LDS), prefetched;
// sumsq parallel across all 256 threads. grid (96, 8, bc), block 256.
__global__ __launch_bounds__(256) void k3_gram(
    const unsigned short* __restrict__ dwo, float* __restrict__ gpart,
    float* __restrict__ ssq)
{
  __shared__ float qs[128 * 32];
  __shared__ float ks[128 * 32];
  const int t = threadIdx.x;
  const int c = blockIdx.x, head = blockIdx.y, bz = blockIdx.z;
  const unsigned short* qp = dwo + ((size_t)bz * C3 + c) * HWC + head * W2;
  const unsigned short* kp = dwo + ((size_t)bz * C3 + CC + c) * HWC + head * W2;

  const int i = t & 31, jg = t >> 5;
  const int scol = t & 31, stens = t >> 7, shq = (t >> 5) & 3;
  float a0 = 0, a1 = 0, a2 = 0, a3 = 0, ss = 0;

  ushort4 qu[4], ku[4];
#pragma unroll
  for (int it = 0; it < 4; ++it) {
    int lin = it * 256 + t;
    int h = lin >> 3, j4 = (lin & 7) * 4;
    qu[it] = *reinterpret_cast<const ushort4*>(qp + h * WW + j4);
    ku[it] = *reinterpret_cast<const ushort4*>(kp + h * WW + j4);
  }

#pragma unroll
  for (int chn = 0; chn < 2; ++chn) {
#pragma unroll
    for (int it = 0; it < 4; ++it) {
      int lin = it * 256 + t;
      int h = lin >> 3, j4 = (lin & 7) * 4;
      *reinterpret_cast<float4*>(&qs[h * 32 + j4]) =
          make_float4(bf2f(qu[it].x), bf2f(qu[it].y), bf2f(qu[it].z), bf2f(qu[it].w));
      *reinterpret_cast<float4*>(&ks[h * 32 + j4]) =
          make_float4(bf2f(ku[it].x), bf2f(ku[it].y), bf2f(ku[it].z), bf2f(ku[it].w));
    }
    if (chn == 0) {
#pragma unroll
      for (int it = 0; it < 4; ++it) {
        int lin = it * 256 + t;
        int h = 128 + (lin >> 3), j4 = (lin & 7) * 4;
        qu[it] = *reinterpret_cast<const ushort4*>(qp + h * WW + j4);
        ku[it] = *reinterpret_cast<const ushort4*>(kp + h * WW + j4);
      }
    }
    __syncthreads();
    for (int h = 0; h < 128; ++h) {
      float qv = qs[h * 32 + i];
      float4 kv = *reinterpret_cast<const float4*>(&ks[h * 32 + jg * 4]);
      a0 = fmaf(qv, kv.x, a0); a1 = fmaf(qv, kv.y, a1);
      a2 = fmaf(qv, kv.z, a2); a3 = fmaf(qv, kv.w, a3);
    }
    {
      const float* src = stens ? ks : qs;
#pragma unroll 8
      for (int k = 0; k < 32; ++k) {
        float v = src[(shq * 32 + k) * 32 + scol];
        ss = fmaf(v, v, ss);
      }
    }
    if (chn == 0) __syncthreads();
  }

  float* gp = gpart + (((size_t)bz * NHEADS + head) * CC + c) * 1024;
  gp[(jg * 4 + 0) * 32 + i] = a0;
  gp[(jg * 4 + 1) * 32 + i] = a1;
  gp[(jg * 4 + 2) * 32 + i] = a2;
  gp[(jg * 4 + 3) * 32 + i] = a3;
  atomicAdd(&ssq[(size_t)bz * 512 + stens * 256 + head * W2 + scol], ss);
}

// K4a: reduce gpart over c -> g[b,h,1024]. grid (8, 8, bc), block 256.
__global__ __launch_bounds__(256) void k4a_reduce(
    const float* __restrict__ gpart, float* __restrict__ g)
{
  __shared__ float l[256];
  const int t = threadIdx.x;
  const int head = blockIdx.x, chunk = blockIdx.y, bz = blockIdx.z;
  const int e = chunk * 128 + (t & 127);
  const int half = t >> 7;
  const float* gp = gpart + (((size_t)bz * NHEADS + head) * CC + half * 48) * 1024 + e;
  float s = 0.f;
#pragma unroll 4
  for (int c = 0; c < 48; ++c) s += gp[(size_t)c * 1024];
  l[t] = s;
  __syncthreads();
  if (t < 128)
    g[((size_t)bz * NHEADS + head) * 1024 + chunk * 128 + t] = l[t] + l[t + 128];
}

// K4b: normalize + temperature + softmax. grid (8, bc), block 64.
__global__ __launch_bounds__(64) void k4b_softmax(
    const float* __restrict__ g, const float* __restrict__ ssq,
    const float* __restrict__ temp, float* __restrict__ attn)
{
  const int t = threadIdx.x;
  const int head = blockIdx.x, bz = blockIdx.y;
  if (t >= 32) return;
  const int i = t;
  const float* gb = g + ((size_t)bz * NHEADS + head) * 1024;
  const float* sq_ = ssq + (size_t)bz * 512 + head * W2;
  const float* sk_ = ssq + (size_t)bz * 512 + 256 + head * W2;
  float invq = 1.f / fmaxf(sqrtf(sq_[i]), 1e-12f);
  float tpq = temp[head] * invq;
  float row[32];
  float m = -1e30f;
#pragma unroll
  for (int j = 0; j < 32; ++j) {
    float invk = 1.f / fmaxf(sqrtf(sk_[j]), 1e-12f);
    float v = gb[j * 32 + i] * tpq * invk;
    row[j] = v;
    m = fmaxf(m, v);
  }
  float ssum = 0;
#pragma unroll
  for (int j = 0; j < 32; ++j) { row[j] = expf(row[j] - m); ssum += row[j]; }
  float inv = 1.f / ssum;
  float* ap = attn + ((size_t)bz * NHEADS + head) * 1024 + i * 32;
#pragma unroll
  for (int j = 0; j < 32; ++j) ap[j] = row[j] * inv;
}

// K5a: t = attn @ v via MFMA. grid (384, bc), block 256 (4 waves).
__global__ __launch_bounds__(256) void k5a_attnv(
    const unsigned short* __restrict__ dwo, const float* __restrict__ attn,
    unsigned short* __restrict__ tbuf)
{
  __shared__ __align__(16) unsigned short vsm[64 * 264];
  __shared__ __align__(16) unsigned short atn_s[256 * 36];
  const int t = threadIdx.x;
  const int tile = blockIdx.x;
  const int bz = blockIdx.y;
  const size_t R0 = (size_t)tile * 64;
  const unsigned short* vsrc = dwo + ((size_t)bz * C3 + 2 * CC) * HWC + R0 * 256;

  us8v vv[8];
#pragma unroll
  for (int j = 0; j < 8; ++j)
    vv[j] = *reinterpret_cast<const us8v*>(vsrc + (size_t)(j * 256 + t) * 8);
  float4 av[8];
  {
    const float* ap = attn + (size_t)bz * 8192 + t * 32;
#pragma unroll
    for (int k = 0; k < 8; ++k)
      av[k] = *reinterpret_cast<const float4*>(ap + k * 4);
  }
  __builtin_amdgcn_sched_barrier(0);
#pragma unroll
  for (int j = 0; j < 8; ++j) {
    int n = j * 256 + t;
    int row = n >> 5, c8 = n & 31;
    *reinterpret_cast<us8v*>(&vsm[row * 264 + c8 * 8]) = vv[j];
  }
#pragma unroll
  for (int k = 0; k < 8; ++k) {
    ushort4 u;
    u.x = f2bf(av[k].x); u.y = f2bf(av[k].y); u.z = f2bf(av[k].z); u.w = f2bf(av[k].w);
    *reinterpret_cast<ushort4*>(&atn_s[t * 36 + k * 4]) = u;
  }
  __syncthreads();

  const int wave = t >> 6, lane = t & 63;
  const int mrow = lane & 15, kg = lane >> 4;

  bf16x8 a[8], b[16];
#pragma unroll
  for (int hd = 0; hd < 8; ++hd)
    a[hd] = *reinterpret_cast<const bf16x8*>(
        &vsm[(wave * 16 + mrow) * 264 + hd * 32 + kg * 8]);
#pragma unroll
  for (int hd = 0; hd < 8; ++hd)
#pragma unroll
    for (int it = 0; it < 2; ++it)
      b[hd * 2 + it] = *reinterpret_cast<const bf16x8*>(
          &atn_s[(hd * 32 + it * 16 + mrow) * 36 + kg * 8]);

  f32x4 acc[16];
#pragma unroll
  for (int q = 0; q < 16; ++q) acc[q] = (f32x4){0.f, 0.f, 0.f, 0.f};
#pragma unroll
  for (int hd = 0; hd < 8; ++hd)
#pragma unroll
    for (int it = 0; it < 2; ++it)
      acc[hd * 2 + it] = __builtin_amdgcn_mfma_f32_16x16x32_bf16(
          a[hd], b[hd * 2 + it], acc[hd * 2 + it], 0, 0, 0);
  __syncthreads();

#pragma unroll
  for (int hd = 0; hd < 8; ++hd)
#pragma unroll
    for (int it = 0; it < 2; ++it) {
      f32x4 v = acc[hd * 2 + it];
      int col = hd * 32 + it * 16 + mrow;
#pragma unroll
      for (int r = 0; r < 4; ++r)
        vsm[(wave * 16 + kg * 4 + r) * 264 + col] = f2bf(v[r]);
    }
  unsigned short* tdst = tbuf + (size_t)bz * CC * HWC + R0 * 256;
#pragma unroll
  for (int k = 0; k < 8; ++k) {
    int n = k * 64 + lane;
    int rloc = n >> 5, c8 = n & 31;
    us8v v = *reinterpret_cast<const us8v*>(&vsm[(wave * 16 + rloc) * 264 + c8 * 8]);
    *reinterpret_cast<us8v*>(tdst + ((size_t)(wave * 16 + rloc)) * 256 + c8 * 8) = v;
  }
}

// K5b v2b: out = proj(t) + pb via MFMA. 64-px tiles x 8, pipelined, 27KB LDS.
// tD spans BOTH As buffers ([96][68] fp32 = 26112B <= 27136B); barrier after store.
__global__ __launch_bounds__(256, 4) void k5b_proj(
    const unsigned short* __restrict__ tbuf, const float* __restrict__ pw,
    const float* __restrict__ pb, float* __restrict__ out, int b0)
{
  __shared__ __align__(16) unsigned short As2[2][64 * 106];
  const int t = threadIdx.x;
  const int bz = blockIdx.y;
  const unsigned short* tb = tbuf + (size_t)bz * CC * HWC;

  const int wave = t >> 6, lane = t & 63;
  const int wm = wave & 1, wn = wave >> 1;
  const int row = lane & 15, kg = lane >> 4;

  bf16x8 bfr[3][3];
  float bias[3];
#pragma unroll
  for (int nt = 0; nt < 3; ++nt) {
    int ocl = wn * 48 + nt * 16 + row;
    bias[nt] = pb[ocl];
#pragma unroll
    for (int kk = 0; kk < 3; ++kk) {
      const float* wp = pw + (size_t)ocl * 96 + kk * 32 + kg * 8;
      float4 w0 = *reinterpret_cast<const float4*>(wp);
      float4 w1 = *reinterpret_cast<const float4*>(wp + 4);
      us8v u;
      u[0] = f2bf(w0.x); u[1] = f2bf(w0.y); u[2] = f2bf(w0.z); u[3] = f2bf(w0.w);
      u[4] = f2bf(w1.x); u[5] = f2bf(w1.y); u[6] = f2bf(w1.z); u[7] = f2bf(w1.w);
      bfr[kk][nt] = *reinterpret_cast<bf16x8*>(&u);
    }
  }

  int sic[3], sp4[3];
#pragma unroll
  for (int r = 0; r < 3; ++r) {
    int lin = r * 256 + t;
    sic[r] = lin >> 4;
    sp4[r] = (lin & 15) * 4;
  }

  int p0 = blockIdx.x * 512;
  ushort4 ua0[3], ua1[3];
#pragma unroll
  for (int r = 0; r < 3; ++r) {
    ua0[r] = *reinterpret_cast<const ushort4*>(tb + (size_t)(2 * sic[r]) * HWC + p0 + sp4[r]);
    ua1[r] = *reinterpret_cast<const ushort4*>(tb + (size_t)(2 * sic[r] + 1) * HWC + p0 + sp4[r]);
  }

  for (int i = 0; i < 8; ++i) {
    unsigned short* Ac = As2[i & 1];
#pragma unroll
    for (int r = 0; r < 3; ++r) {
      unsigned short a0[4] = {ua0[r].x, ua0[r].y, ua0[r].z, ua0[r].w};
      unsigned short a1[4] = {ua1[r].x, ua1[r].y, ua1[r].z, ua1[r].w};
#pragma unroll
      for (int j = 0; j < 4; ++j) {
        unsigned pk = (unsigned)a0[j] | ((unsigned)a1[j] << 16);
        *reinterpret_cast<unsigned*>(&Ac[(sp4[r] + j) * 106 + 2 * sic[r]]) = pk;
      }
    }
    if (i < 7) {
      int p0n = p0 + 64;
#pragma unroll
      for (int r = 0; r < 3; ++r) {
        ua0[r] = *reinterpret_cast<const ushort4*>(tb + (size_t)(2 * sic[r]) * HWC + p0n + sp4[r]);
        ua1[r] = *reinterpret_cast<const ushort4*>(tb + (size_t)(2 * sic[r] + 1) * HWC + p0n + sp4[r]);
      }
    }
    __syncthreads();

    f32x4 acc[2][3];
#pragma unroll
    for (int mt = 0; mt < 2; ++mt)
#pragma unroll
      for (int nt = 0; nt < 3; ++nt) acc[mt][nt] = (f32x4){0.f, 0.f, 0.f, 0.f};
#pragma unroll
    for (int kk = 0; kk < 3; ++kk) {
      bf16x8 a[2];
#pragma unroll
      for (int mt = 0; mt < 2; ++mt)
        a[mt] = *reinterpret_cast<const bf16x8*>(
            &Ac[(wm * 32 + mt * 16 + row) * 106 + kk * 32 + kg * 8]);
#pragma unroll
      for (int mt = 0; mt < 2; ++mt)
#pragma unroll
        for (int nt = 0; nt < 3; ++nt)
          acc[mt][nt] = __builtin_amdgcn_mfma_f32_16x16x32_bf16(
              a[mt], bfr[kk][nt], acc[mt][nt], 0, 0, 0);
    }
    __syncthreads();   // MFMA reads done; tD spans both buffers

    float* tD = (float*)As2;   // [96][68] fp32, 26112B <= 27136B
#pragma unroll
    for (int nt = 0; nt < 3; ++nt) {
      int ocl = wn * 48 + nt * 16 + row;
      float bv = bias[nt];
#pragma unroll
      for (int mt = 0; mt < 2; ++mt) {
        int pxl = wm * 32 + mt * 16 + kg * 4;
        f32x4 v = acc[mt][nt];
        float4 w = make_float4(v[0] + bv, v[1] + bv, v[2] + bv, v[3] + bv);
        *reinterpret_cast<float4*>(&tD[ocl * 68 + pxl]) = w;
      }
    }
    __syncthreads();
    float* ob = out + (size_t)(b0 + bz) * CC * HWC + p0;
#pragma unroll
    for (int r = 0; r < 6; ++r) {
      int lin = r * 256 + t;
      int o = lin >> 4, p4 = (lin & 15) * 4;
      float4 v = *reinterpret_cast<const float4*>(&tD[o * 68 + p4]);
      *reinterpret_cast<float4*>(ob + (size_t)o * HWC + p4) = v;
    }
    __syncthreads();   // store-readback done before next cvt overwrites span
    p0 += 64;
  }
}

extern "C" void kernel_launch(void* const* d_in, const int* in_sizes, int n_in,
                              void* d_out, int out_size, void* d_ws, size_t ws_size,
                              hipStream_t stream)
{
  const float* x      = (const float*)d_in[0];
  const float* qkv_w  = (const float*)d_in[1];
  const float* qkv_b  = (const float*)d_in[2];
  const float* dw_w   = (const float*)d_in[3];
  const float* dw_b   = (const float*)d_in[4];
  const float* proj_w = (const float*)d_in[5];
  const float* proj_b = (const float*)d_in[6];
  const float* temp   = (const float*)d_in[7];
  float* out = (float*)d_out;

  const size_t per_pre  = (size_t)C3 * HWC * 2;
  const size_t per_gp   = (size_t)NHEADS * CC * 1024 * 4;
  const size_t per_ssq  = (size_t)2 * 256 * 4;
  const size_t per_attn = (size_t)NHEADS * 1024 * 4;
  const size_t per_g    = (size_t)NHEADS * 1024 * 4;
  const size_t per_b = per_pre * 2 + per_gp + per_ssq + per_attn + per_g;

  int bc = 4;
  while (bc > 1 && per_b * (size_t)bc > ws_size) bc >>= 1;

  char* p = (char*)d_ws;
  unsigned short* pre = (unsigned short*)p; p += per_pre * bc;
  unsigned short* dwo = (unsigned short*)p; p += per_pre * bc;
  float* gpart = (float*)p; p += per_gp * bc;
  float* ssq   = (float*)p; p += per_ssq * bc;
  float* attn  = (float*)p; p += per_attn * bc;
  float* g     = (float*)p; p += per_g * bc;
  unsigned short* tbuf = pre;

  for (int b0 = 0; b0 < 4; b0 += bc) {
    k1_qkv_mfma<<<dim3(128, 3, bc), 256, 0, stream>>>(x, qkv_w, qkv_b, pre, b0);
    k2_dw<<<dim3(C3, 8, bc), 256, 0, stream>>>(pre, dw_w, dw_b, dwo);
    hipMemsetAsync(ssq, 0, per_ssq * bc, stream);
    k3_gram<<<dim3(CC, NHEADS, bc), 256, 0, stream>>>(dwo, gpart, ssq);
    k4a_reduce<<<dim3(NHEADS, 8, bc), 256, 0, stream>>>(gpart, g);
    k4b_softmax<<<dim3(NHEADS, bc), 64, 0, stream>>>(g, ssq, temp, attn);
    k5a_attnv<<<dim3(384, bc), 256, 0, stream>>>(dwo, attn, tbuf);
    k5b_proj<<<dim3(128, bc), 256, 0, stream>>>(tbuf, proj_w, proj_b, out, b0);
  }
}

// Round 10
// 222.726 us; speedup vs baseline: 1.2563x; 1.2563x over previous
//
#include <hip/hip_runtime.h>

#define CC 96
#define C3 288
#define HH 256
#define WW 256
#define HWC 65536
#define NHEADS 8
#define W2 32

typedef __bf16 bf16x8 __attribute__((ext_vector_type(8)));
typedef float f32x4 __attribute__((ext_vector_type(4)));
typedef unsigned short us8v __attribute__((ext_vector_type(8)));

__device__ __forceinline__ float bf2f(unsigned short u) {
  return __uint_as_float(((unsigned)u) << 16);
}
__device__ __forceinline__ unsigned short f2bf(float f) {
  unsigned u = __float_as_uint(f);
  unsigned r = u + 0x7fffu + ((u >> 16) & 1u);
  return (unsigned short)(r >> 16);
}

// K1 v4b: qkv conv1x1 via bf16 MFMA. 64-px tiles x 8, pipelined, 27KB LDS.
__global__ __launch_bounds__(256, 4) void k1_qkv_mfma(
    const float* __restrict__ x, const float* __restrict__ qw,
    const float* __restrict__ qb, unsigned short* __restrict__ pre, int b0)
{
  __shared__ __align__(16) unsigned short As2[2][64 * 106];
  const int t = threadIdx.x;
  const int o0 = blockIdx.y * 96;
  const int bz = blockIdx.z;
  const float* xb = x + (size_t)(b0 + bz) * CC * HWC;

  const int wave = t >> 6, lane = t & 63;
  const int wm = wave & 1, wn = wave >> 1;
  const int row = lane & 15, kg = lane >> 4;

  bf16x8 bfr[3][3];
  float bias[3];
#pragma unroll
  for (int nt = 0; nt < 3; ++nt) {
    int ocl = wn * 48 + nt * 16 + row;
    bias[nt] = qb[o0 + ocl];
#pragma unroll
    for (int kk = 0; kk < 3; ++kk) {
      const float* wp = qw + (size_t)(o0 + ocl) * 96 + kk * 32 + kg * 8;
      float4 w0 = *reinterpret_cast<const float4*>(wp);
      float4 w1 = *reinterpret_cast<const float4*>(wp + 4);
      us8v u;
      u[0] = f2bf(w0.x); u[1] = f2bf(w0.y); u[2] = f2bf(w0.z); u[3] = f2bf(w0.w);
      u[4] = f2bf(w1.x); u[5] = f2bf(w1.y); u[6] = f2bf(w1.z); u[7] = f2bf(w1.w);
      bfr[kk][nt] = *reinterpret_cast<bf16x8*>(&u);
    }
  }

  int sic[3], sp4[3];
#pragma unroll
  for (int r = 0; r < 3; ++r) {
    int lin = r * 256 + t;
    sic[r] = lin >> 4;
    sp4[r] = (lin & 15) * 4;
  }

  int p0 = blockIdx.x * 512;
  float4 va0[3], va1[3];
#pragma unroll
  for (int r = 0; r < 3; ++r) {
    va0[r] = *reinterpret_cast<const float4*>(xb + (size_t)(2 * sic[r]) * HWC + p0 + sp4[r]);
    va1[r] = *reinterpret_cast<const float4*>(xb + (size_t)(2 * sic[r] + 1) * HWC + p0 + sp4[r]);
  }

  for (int i = 0; i < 8; ++i) {
    unsigned short* Ac = As2[i & 1];
#pragma unroll
    for (int r = 0; r < 3; ++r) {
      float a0[4] = {va0[r].x, va0[r].y, va0[r].z, va0[r].w};
      float a1[4] = {va1[r].x, va1[r].y, va1[r].z, va1[r].w};
#pragma unroll
      for (int j = 0; j < 4; ++j) {
        unsigned pk = (unsigned)f2bf(a0[j]) | ((unsigned)f2bf(a1[j]) << 16);
        *reinterpret_cast<unsigned*>(&Ac[(sp4[r] + j) * 106 + 2 * sic[r]]) = pk;
      }
    }
    if (i < 7) {
      int p0n = p0 + 64;
#pragma unroll
      for (int r = 0; r < 3; ++r) {
        va0[r] = *reinterpret_cast<const float4*>(xb + (size_t)(2 * sic[r]) * HWC + p0n + sp4[r]);
        va1[r] = *reinterpret_cast<const float4*>(xb + (size_t)(2 * sic[r] + 1) * HWC + p0n + sp4[r]);
      }
    }
    __syncthreads();

    f32x4 acc[2][3];
#pragma unroll
    for (int mt = 0; mt < 2; ++mt)
#pragma unroll
      for (int nt = 0; nt < 3; ++nt) acc[mt][nt] = (f32x4){0.f, 0.f, 0.f, 0.f};
#pragma unroll
    for (int kk = 0; kk < 3; ++kk) {
      bf16x8 a[2];
#pragma unroll
      for (int mt = 0; mt < 2; ++mt)
        a[mt] = *reinterpret_cast<const bf16x8*>(
            &Ac[(wm * 32 + mt * 16 + row) * 106 + kk * 32 + kg * 8]);
#pragma unroll
      for (int mt = 0; mt < 2; ++mt)
#pragma unroll
        for (int nt = 0; nt < 3; ++nt)
          acc[mt][nt] = __builtin_amdgcn_mfma_f32_16x16x32_bf16(
              a[mt], bfr[kk][nt], acc[mt][nt], 0, 0, 0);
    }
    __syncthreads();

    unsigned short* tD = (unsigned short*)As2;   // [96][72]
#pragma unroll
    for (int nt = 0; nt < 3; ++nt) {
      int ocl = wn * 48 + nt * 16 + row;
      float bv = bias[nt];
#pragma unroll
      for (int mt = 0; mt < 2; ++mt) {
        int pxl = wm * 32 + mt * 16 + kg * 4;
        f32x4 v = acc[mt][nt];
        unsigned pk0 = (unsigned)f2bf(v[0] + bv) | ((unsigned)f2bf(v[1] + bv) << 16);
        unsigned pk1 = (unsigned)f2bf(v[2] + bv) | ((unsigned)f2bf(v[3] + bv) << 16);
        *reinterpret_cast<unsigned*>(&tD[ocl * 72 + pxl]) = pk0;
        *reinterpret_cast<unsigned*>(&tD[ocl * 72 + pxl + 2]) = pk1;
      }
    }
    __syncthreads();
    unsigned short* preb = pre + ((size_t)bz * C3 + o0) * HWC + p0;
#pragma unroll
    for (int r = 0; r < 3; ++r) {
      int lin = r * 256 + t;
      int oc = lin >> 3, ch = lin & 7;
      us8v v = *reinterpret_cast<const us8v*>(&tD[oc * 72 + ch * 8]);
      *reinterpret_cast<us8v*>(preb + (size_t)oc * HWC + ch * 8) = v;
    }
    __syncthreads();
    p0 += 64;
  }
}

// K2: depthwise 3x3 + bias, LDS-free register-rolling. grid (288, 8, bc).
__global__ __launch_bounds__(256) void k2_dw(
    const unsigned short* __restrict__ pre, const float* __restrict__ dww,
    const float* __restrict__ dwb, unsigned short* __restrict__ dwo)
{
  const int t = threadIdx.x;
  const int c3 = blockIdx.x;
  const int hb = blockIdx.y;
  const int bz = blockIdx.z;
  const size_t choff = ((size_t)bz * C3 + c3) * HWC;
  const int team = t >> 5, tl = t & 31;
  const int h0 = hb * 32 + team * 4;

  us8v rin[6];
#pragma unroll
  for (int r = 0; r < 6; ++r) {
    int hh = h0 - 1 + r;
    if (hh >= 0 && hh < HH)
      rin[r] = *reinterpret_cast<const us8v*>(pre + choff + (size_t)hh * WW + tl * 8);
    else
      rin[r] = (us8v){0, 0, 0, 0, 0, 0, 0, 0};
  }

  float wg[9];
#pragma unroll
  for (int i = 0; i < 9; ++i) wg[i] = dww[c3 * 9 + i];
  const float bias = dwb[c3];

  float f[6][8];
  float lf[6], rt[6];
#pragma unroll
  for (int r = 0; r < 6; ++r) {
#pragma unroll
    for (int j = 0; j < 8; ++j) f[r][j] = bf2f(rin[r][j]);
    float l = __shfl_up(f[r][7], 1, 32);
    float rr = __shfl_down(f[r][0], 1, 32);
    lf[r] = (tl == 0) ? 0.f : l;
    rt[r] = (tl == 31) ? 0.f : rr;
  }

#pragma unroll
  for (int orow = 0; orow < 4; ++orow) {
    float o[8];
#pragma unroll
    for (int j = 0; j < 8; ++j) o[j] = bias;
#pragma unroll
    for (int k = 0; k < 3; ++k) {
      const int r = orow + k;
      const float w0 = wg[k * 3 + 0], w1 = wg[k * 3 + 1], w2 = wg[k * 3 + 2];
      o[0] = fmaf(lf[r], w0, fmaf(f[r][0], w1, fmaf(f[r][1], w2, o[0])));
#pragma unroll
      for (int j = 1; j < 7; ++j)
        o[j] = fmaf(f[r][j - 1], w0, fmaf(f[r][j], w1, fmaf(f[r][j + 1], w2, o[j])));
      o[7] = fmaf(f[r][6], w0, fmaf(f[r][7], w1, fmaf(rt[r], w2, o[7])));
    }
    us8v u;
#pragma unroll
    for (int j = 0; j < 8; ++j) u[j] = f2bf(o[j]);
    *reinterpret_cast<us8v*>((unsigned short*)dwo + choff + (size_t)(h0 + orow) * WW + tl * 8) = u;
  }
}

// K3 v3: Gram via bf16 MFMA. grid (24, 8, bc), block 256 (4 waves).
// Block: (c-group of 4, head, b). Wave = one 16x16 quadrant (mt,nt).
// q,k tiles transposed to LDS [i][264] bf16 via pack-pair u32 writes;
// c+1 loads prefetched in regs; sumsq fused; partial Gram atomicAdd -> g.
__global__ __launch_bounds__(256, 4) void k3_gram(
    const unsigned short* __restrict__ dwo, float* __restrict__ g,
    float* __restrict__ ssq)
{
  __shared__ __align__(16) unsigned short qT[32 * 264];
  __shared__ __align__(16) unsigned short kT[32 * 264];
  const int t = threadIdx.x;
  const int cg0 = blockIdx.x;          // c = cg0*4 + cc
  const int head = blockIdx.y, bz = blockIdx.z;
  const int lane = t & 63, wave = t >> 6;
  const int mt = wave & 1, nt = wave >> 1;
  const int l15 = lane & 15, l4 = lane >> 4;
  const int cg = t & 7;                // col group (4 cols)
  int rp[4];
#pragma unroll
  for (int r = 0; r < 4; ++r) rp[r] = (r * 256 + t) >> 3;   // row-pair 0..127

  const unsigned short* qbase = dwo + ((size_t)bz * C3 + cg0 * 4) * HWC + head * W2;
  const unsigned short* kbase = qbase + (size_t)CC * HWC;

  ushort4 qa[4], qb_[4], ka[4], kb_[4];
#pragma unroll
  for (int r = 0; r < 4; ++r) {
    qa[r] = *reinterpret_cast<const ushort4*>(qbase + (size_t)(2 * rp[r]) * WW + cg * 4);
    qb_[r] = *reinterpret_cast<const ushort4*>(qbase + (size_t)(2 * rp[r] + 1) * WW + cg * 4);
    ka[r] = *reinterpret_cast<const ushort4*>(kbase + (size_t)(2 * rp[r]) * WW + cg * 4);
    kb_[r] = *reinterpret_cast<const ushort4*>(kbase + (size_t)(2 * rp[r] + 1) * WW + cg * 4);
  }

  f32x4 acc = (f32x4){0.f, 0.f, 0.f, 0.f};
  float ssum_q = 0.f, ssum_k = 0.f;

  for (int cc = 0; cc < 4; ++cc) {
    // transpose-stage current c (pack h-pairs into u32)
#pragma unroll
    for (int r = 0; r < 4; ++r) {
      unsigned short aq0[4] = {qa[r].x, qa[r].y, qa[r].z, qa[r].w};
      unsigned short aq1[4] = {qb_[r].x, qb_[r].y, qb_[r].z, qb_[r].w};
      unsigned short ak0[4] = {ka[r].x, ka[r].y, ka[r].z, ka[r].w};
      unsigned short ak1[4] = {kb_[r].x, kb_[r].y, kb_[r].z, kb_[r].w};
#pragma unroll
      for (int j = 0; j < 4; ++j) {
        int dwi = (cg * 4 + j) * 132 + rp[r];
        *(reinterpret_cast<unsigned*>(qT) + dwi) =
            (unsigned)aq0[j] | ((unsigned)aq1[j] << 16);
        *(reinterpret_cast<unsigned*>(kT) + dwi) =
            (unsigned)ak0[j] | ((unsigned)ak1[j] << 16);
      }
    }
    // prefetch next c
    if (cc < 3) {
      const unsigned short* qn = qbase + (size_t)(cc + 1) * HWC;
      const unsigned short* kn = kbase + (size_t)(cc + 1) * HWC;
#pragma unroll
      for (int r = 0; r < 4; ++r) {
        qa[r] = *reinterpret_cast<const ushort4*>(qn + (size_t)(2 * rp[r]) * WW + cg * 4);
        qb_[r] = *reinterpret_cast<const ushort4*>(qn + (size_t)(2 * rp[r] + 1) * WW + cg * 4);
        ka[r] = *reinterpret_cast<const ushort4*>(kn + (size_t)(2 * rp[r]) * WW + cg * 4);
        kb_[r] = *reinterpret_cast<const ushort4*>(kn + (size_t)(2 * rp[r] + 1) * WW + cg * 4);
      }
    }
    __syncthreads();
    // MFMA over K=256 (8 chunks of 32)
#pragma unroll
    for (int kk = 0; kk < 8; ++kk) {
      bf16x8 a = *reinterpret_cast<const bf16x8*>(
          &qT[(mt * 16 + l15) * 264 + kk * 32 + l4 * 8]);
      bf16x8 b = *reinterpret_cast<const bf16x8*>(
          &kT[(nt * 16 + l15) * 264 + kk * 32 + l4 * 8]);
      acc = __builtin_amdgcn_mfma_f32_16x16x32_bf16(a, b, acc, 0, 0, 0);
    }
    // fused sumsq: thread t covers col i=t&31, h-segment t>>5
    {
      const int i = t & 31, seg = t >> 5;
#pragma unroll
      for (int m = 0; m < 4; ++m) {
        us8v vq = *reinterpret_cast<const us8v*>(&qT[i * 264 + seg * 32 + m * 8]);
        us8v vk = *reinterpret_cast<const us8v*>(&kT[i * 264 + seg * 32 + m * 8]);
#pragma unroll
        for (int e = 0; e < 8; ++e) {
          float fq = bf2f(vq[e]), fk = bf2f(vk[e]);
          ssum_q = fmaf(fq, fq, ssum_q);
          ssum_k = fmaf(fk, fk, ssum_k);
        }
      }
    }
    __syncthreads();
  }

  // Gram partial -> g via atomics. D: m=i=mt*16+l4*4+reg, n=j=nt*16+l15.
  float* gb = g + ((size_t)bz * NHEADS + head) * 1024;
#pragma unroll
  for (int reg = 0; reg < 4; ++reg)
    atomicAdd(&gb[(nt * 16 + l15) * 32 + mt * 16 + l4 * 4 + reg], acc[reg]);

  // sumsq block-reduce (reuse qT as float scratch)
  float* red = reinterpret_cast<float*>(qT);
  red[t] = ssum_q;
  red[256 + t] = ssum_k;
  __syncthreads();
  if (t < 32) {
    float sq = 0.f, sk = 0.f;
#pragma unroll
    for (int p = 0; p < 8; ++p) { sq += red[t + 32 * p]; sk += red[256 + t + 32 * p]; }
    atomicAdd(&ssq[(size_t)bz * 512 + head * W2 + t], sq);
    atomicAdd(&ssq[(size_t)bz * 512 + 256 + head * W2 + t], sk);
  }
}

// K4b: normalize + temperature + softmax. grid (8, bc), block 64.
__global__ __launch_bounds__(64) void k4b_softmax(
    const float* __restrict__ g, const float* __restrict__ ssq,
    const float* __restrict__ temp, float* __restrict__ attn)
{
  const int t = threadIdx.x;
  const int head = blockIdx.x, bz = blockIdx.y;
  if (t >= 32) return;
  const int i = t;
  const float* gb = g + ((size_t)bz * NHEADS + head) * 1024;
  const float* sq_ = ssq + (size_t)bz * 512 + head * W2;
  const float* sk_ = ssq + (size_t)bz * 512 + 256 + head * W2;
  float invq = 1.f / fmaxf(sqrtf(sq_[i]), 1e-12f);
  float tpq = temp[head] * invq;
  float row[32];
  float m = -1e30f;
#pragma unroll
  for (int j = 0; j < 32; ++j) {
    float invk = 1.f / fmaxf(sqrtf(sk_[j]), 1e-12f);
    float v = gb[j * 32 + i] * tpq * invk;
    row[j] = v;
    m = fmaxf(m, v);
  }
  float ssum = 0;
#pragma unroll
  for (int j = 0; j < 32; ++j) { row[j] = expf(row[j] - m); ssum += row[j]; }
  float inv = 1.f / ssum;
  float* ap = attn + ((size_t)bz * NHEADS + head) * 1024 + i * 32;
#pragma unroll
  for (int j = 0; j < 32; ++j) ap[j] = row[j] * inv;
}

// K5a: t = attn @ v via MFMA. grid (384, bc), block 256 (4 waves).
__global__ __launch_bounds__(256) void k5a_attnv(
    const unsigned short* __restrict__ dwo, const float* __restrict__ attn,
    unsigned short* __restrict__ tbuf)
{
  __shared__ __align__(16) unsigned short vsm[64 * 264];
  __shared__ __align__(16) unsigned short atn_s[256 * 36];
  const int t = threadIdx.x;
  const int tile = blockIdx.x;
  const int bz = blockIdx.y;
  const size_t R0 = (size_t)tile * 64;
  const unsigned short* vsrc = dwo + ((size_t)bz * C3 + 2 * CC) * HWC + R0 * 256;

  us8v vv[8];
#pragma unroll
  for (int j = 0; j < 8; ++j)
    vv[j] = *reinterpret_cast<const us8v*>(vsrc + (size_t)(j * 256 + t) * 8);
  float4 av[8];
  {
    const float* ap = attn + (size_t)bz * 8192 + t * 32;
#pragma unroll
    for (int k = 0; k < 8; ++k)
      av[k] = *reinterpret_cast<const float4*>(ap + k * 4);
  }
  __builtin_amdgcn_sched_barrier(0);
#pragma unroll
  for (int j = 0; j < 8; ++j) {
    int n = j * 256 + t;
    int row = n >> 5, c8 = n & 31;
    *reinterpret_cast<us8v*>(&vsm[row * 264 + c8 * 8]) = vv[j];
  }
#pragma unroll
  for (int k = 0; k < 8; ++k) {
    ushort4 u;
    u.x = f2bf(av[k].x); u.y = f2bf(av[k].y); u.z = f2bf(av[k].z); u.w = f2bf(av[k].w);
    *reinterpret_cast<ushort4*>(&atn_s[t * 36 + k * 4]) = u;
  }
  __syncthreads();

  const int wave = t >> 6, lane = t & 63;
  const int mrow = lane & 15, kg = lane >> 4;

  bf16x8 a[8], b[16];
#pragma unroll
  for (int hd = 0; hd < 8; ++hd)
    a[hd] = *reinterpret_cast<const bf16x8*>(
        &vsm[(wave * 16 + mrow) * 264 + hd * 32 + kg * 8]);
#pragma unroll
  for (int hd = 0; hd < 8; ++hd)
#pragma unroll
    for (int it = 0; it < 2; ++it)
      b[hd * 2 + it] = *reinterpret_cast<const bf16x8*>(
          &atn_s[(hd * 32 + it * 16 + mrow) * 36 + kg * 8]);

  f32x4 acc[16];
#pragma unroll
  for (int q = 0; q < 16; ++q) acc[q] = (f32x4){0.f, 0.f, 0.f, 0.f};
#pragma unroll
  for (int hd = 0; hd < 8; ++hd)
#pragma unroll
    for (int it = 0; it < 2; ++it)
      acc[hd * 2 + it] = __builtin_amdgcn_mfma_f32_16x16x32_bf16(
          a[hd], b[hd * 2 + it], acc[hd * 2 + it], 0, 0, 0);
  __syncthreads();

#pragma unroll
  for (int hd = 0; hd < 8; ++hd)
#pragma unroll
    for (int it = 0; it < 2; ++it) {
      f32x4 v = acc[hd * 2 + it];
      int col = hd * 32 + it * 16 + mrow;
#pragma unroll
      for (int r = 0; r < 4; ++r)
        vsm[(wave * 16 + kg * 4 + r) * 264 + col] = f2bf(v[r]);
    }
  unsigned short* tdst = tbuf + (size_t)bz * CC * HWC + R0 * 256;
#pragma unroll
  for (int k = 0; k < 8; ++k) {
    int n = k * 64 + lane;
    int rloc = n >> 5, c8 = n & 31;
    us8v v = *reinterpret_cast<const us8v*>(&vsm[(wave * 16 + rloc) * 264 + c8 * 8]);
    *reinterpret_cast<us8v*>(tdst + ((size_t)(wave * 16 + rloc)) * 256 + c8 * 8) = v;
  }
}

// K5b v2b: out = proj(t) + pb via MFMA. 64-px tiles x 8, pipelined, 27KB LDS.
__global__ __launch_bounds__(256, 4) void k5b_proj(
    const unsigned short* __restrict__ tbuf, const float* __restrict__ pw,
    const float* __restrict__ pb, float* __restrict__ out, int b0)
{
  __shared__ __align__(16) unsigned short As2[2][64 * 106];
  const int t = threadIdx.x;
  const int bz = blockIdx.y;
  const unsigned short* tb = tbuf + (size_t)bz * CC * HWC;

  const int wave = t >> 6, lane = t & 63;
  const int wm = wave & 1, wn = wave >> 1;
  const int row = lane & 15, kg = lane >> 4;

  bf16x8 bfr[3][3];
  float bias[3];
#pragma unroll
  for (int nt = 0; nt < 3; ++nt) {
    int ocl = wn * 48 + nt * 16 + row;
    bias[nt] = pb[ocl];
#pragma unroll
    for (int kk = 0; kk < 3; ++kk) {
      const float* wp = pw + (size_t)ocl * 96 + kk * 32 + kg * 8;
      float4 w0 = *reinterpret_cast<const float4*>(wp);
      float4 w1 = *reinterpret_cast<const float4*>(wp + 4);
      us8v u;
      u[0] = f2bf(w0.x); u[1] = f2bf(w0.y); u[2] = f2bf(w0.z); u[3] = f2bf(w0.w);
      u[4] = f2bf(w1.x); u[5] = f2bf(w1.y); u[6] = f2bf(w1.z); u[7] = f2bf(w1.w);
      bfr[kk][nt] = *reinterpret_cast<bf16x8*>(&u);
    }
  }

  int sic[3], sp4[3];
#pragma unroll
  for (int r = 0; r < 3; ++r) {
    int lin = r * 256 + t;
    sic[r] = lin >> 4;
    sp4[r] = (lin & 15) * 4;
  }

  int p0 = blockIdx.x * 512;
  ushort4 ua0[3], ua1[3];
#pragma unroll
  for (int r = 0; r < 3; ++r) {
    ua0[r] = *reinterpret_cast<const ushort4*>(tb + (size_t)(2 * sic[r]) * HWC + p0 + sp4[r]);
    ua1[r] = *reinterpret_cast<const ushort4*>(tb + (size_t)(2 * sic[r] + 1) * HWC + p0 + sp4[r]);
  }

  for (int i = 0; i < 8; ++i) {
    unsigned short* Ac = As2[i & 1];
#pragma unroll
    for (int r = 0; r < 3; ++r) {
      unsigned short a0[4] = {ua0[r].x, ua0[r].y, ua0[r].z, ua0[r].w};
      unsigned short a1[4] = {ua1[r].x, ua1[r].y, ua1[r].z, ua1[r].w};
#pragma unroll
      for (int j = 0; j < 4; ++j) {
        unsigned pk = (unsigned)a0[j] | ((unsigned)a1[j] << 16);
        *reinterpret_cast<unsigned*>(&Ac[(sp4[r] + j) * 106 + 2 * sic[r]]) = pk;
      }
    }
    if (i < 7) {
      int p0n = p0 + 64;
#pragma unroll
      for (int r = 0; r < 3; ++r) {
        ua0[r] = *reinterpret_cast<const ushort4*>(tb + (size_t)(2 * sic[r]) * HWC + p0n + sp4[r]);
        ua1[r] = *reinterpret_cast<const ushort4*>(tb + (size_t)(2 * sic[r] + 1) * HWC + p0n + sp4[r]);
      }
    }
    __syncthreads();

    f32x4 acc[2][3];
#pragma unroll
    for (int mt = 0; mt < 2; ++mt)
#pragma unroll
      for (int nt = 0; nt < 3; ++nt) acc[mt][nt] = (f32x4){0.f, 0.f, 0.f, 0.f};
#pragma unroll
    for (int kk = 0; kk < 3; ++kk) {
      bf16x8 a[2];
#pragma unroll
      for (int mt = 0; mt < 2; ++mt)
        a[mt] = *reinterpret_cast<const bf16x8*>(
            &Ac[(wm * 32 + mt * 16 + row) * 106 + kk * 32 + kg * 8]);
#pragma unroll
      for (int mt = 0; mt < 2; ++mt)
#pragma unroll
        for (int nt = 0; nt < 3; ++nt)
          acc[mt][nt] = __builtin_amdgcn_mfma_f32_16x16x32_bf16(
              a[mt], bfr[kk][nt], acc[mt][nt], 0, 0, 0);
    }
    __syncthreads();

    float* tD = (float*)As2;   // [96][68] fp32
#pragma unroll
    for (int nt = 0; nt < 3; ++nt) {
      int ocl = wn * 48 + nt * 16 + row;
      float bv = bias[nt];
#pragma unroll
      for (int mt = 0; mt < 2; ++mt) {
        int pxl = wm * 32 + mt * 16 + kg * 4;
        f32x4 v = acc[mt][nt];
        float4 w = make_float4(v[0] + bv, v[1] + bv, v[2] + bv, v[3] + bv);
        *reinterpret_cast<float4*>(&tD[ocl * 68 + pxl]) = w;
      }
    }
    __syncthreads();
    float* ob = out + (size_t)(b0 + bz) * CC * HWC + p0;
#pragma unroll
    for (int r = 0; r < 6; ++r) {
      int lin = r * 256 + t;
      int o = lin >> 4, p4 = (lin & 15) * 4;
      float4 v = *reinterpret_cast<const float4*>(&tD[o * 68 + p4]);
      *reinterpret_cast<float4*>(ob + (size_t)o * HWC + p4) = v;
    }
    __syncthreads();
    p0 += 64;
  }
}

extern "C" void kernel_launch(void* const* d_in, const int* in_sizes, int n_in,
                              void* d_out, int out_size, void* d_ws, size_t ws_size,
                              hipStream_t stream)
{
  const float* x      = (const float*)d_in[0];
  const float* qkv_w  = (const float*)d_in[1];
  const float* qkv_b  = (const float*)d_in[2];
  const float* dw_w   = (const float*)d_in[3];
  const float* dw_b   = (const float*)d_in[4];
  const float* proj_w = (const float*)d_in[5];
  const float* proj_b = (const float*)d_in[6];
  const float* temp   = (const float*)d_in[7];
  float* out = (float*)d_out;

  const size_t per_pre  = (size_t)C3 * HWC * 2;
  const size_t per_ssq  = (size_t)2 * 256 * 4;
  const size_t per_attn = (size_t)NHEADS * 1024 * 4;
  const size_t per_g    = (size_t)NHEADS * 1024 * 4;
  const size_t per_b = per_pre * 2 + per_ssq + per_attn + per_g;

  int bc = 4;
  while (bc > 1 && per_b * (size_t)bc > ws_size) bc >>= 1;

  char* p = (char*)d_ws;
  unsigned short* pre = (unsigned short*)p; p += per_pre * bc;
  unsigned short* dwo = (unsigned short*)p; p += per_pre * bc;
  float* ssq   = (float*)p; p += per_ssq * bc;
  float* attn  = (float*)p; p += per_attn * bc;
  float* g     = (float*)p; p += per_g * bc;
  unsigned short* tbuf = pre;

  for (int b0 = 0; b0 < 4; b0 += bc) {
    k1_qkv_mfma<<<dim3(128, 3, bc), 256, 0, stream>>>(x, qkv_w, qkv_b, pre, b0);
    k2_dw<<<dim3(C3, 8, bc), 256, 0, stream>>>(pre, dw_w, dw_b, dwo);
    hipMemsetAsync(ssq, 0, per_ssq * bc, stream);
    hipMemsetAsync(g, 0, per_g * bc, stream);
    k3_gram<<<dim3(24, NHEADS, bc), 256, 0, stream>>>(dwo, g, ssq);
    k4b_softmax<<<dim3(NHEADS, bc), 64, 0, stream>>>(g, ssq, temp, attn);
    k5a_attnv<<<dim3(384, bc), 256, 0, stream>>>(dwo, attn, tbuf);
    k5b_proj<<<dim3(128, bc), 256, 0, stream>>>(tbuf, proj_w, proj_b, out, b0);
  }
}